// Round 1
// 93.962 us; speedup vs baseline: 1.1148x; 1.1148x over previous
//
#include <hip/hip_runtime.h>
#include <math.h>

// Problem constants (fixed by the reference file)
constexpr int B  = 1024;
constexpr int NL = 64;
constexpr int W  = 2048;
constexpr int INNER = NL - 2;            // layers 1..62 inclusive -> 62 layers
constexpr float EPS_N = 1e-8f;
constexpr float EPS_Y = 1e-9f;

typedef float v2f __attribute__((ext_vector_type(2)));

// Two wavelengths per thread; state packed ACROSS wavelengths so every VOP3P
// operand is a natural VGPR pair:
//   av=(a_w0,a_w1) bv=(b_w0,b_w1) cv=(c_w0,c_w1) dv=(d_w0,d_w1)
// with M = [[a, i*b],[i*c, d]] (closed form under layer products, all real).
// Per-layer constants are stored PRE-DUPLICATED in LDS as pairs
//   (nd,nd,n,n) and (rc,rc)  with rc = 1/(n+eps)
// so phi/ns/sn are single v_pk_mul off the ds_read with no v_mov duplication.
// Update per layer (signs fold into VOP3P neg modifiers):
//   a' = a*c + b*(n*s);  b' = b*c - a*(s/n)
//   c' = c*c - d*(n*s);  d' = d*c + c*(s/n)
// phi tracked in REVOLUTIONS so v_sin_f32/v_cos_f32 are single trans ops.
__global__ __launch_bounds__(256)
void tmm_kernel(const float* __restrict__ n_layers,
                const float* __restrict__ d_layers,
                const float* __restrict__ wavelengths,
                float* __restrict__ out)
{
    __shared__ float4 s_layer[INNER][2];   // [i][0]=(nd,nd,n,n) [i][1]=(rc,rc,0,0)
    __shared__ float  s_edge[2];           // n_in, n_sub

    const int b   = blockIdx.y;
    const int tid = threadIdx.x;
    const int w0  = blockIdx.x * 512 + tid * 2;

    if (tid < INNER) {
        const float n  = n_layers[b * NL + 1 + tid];
        const float d  = d_layers[b * NL + 1 + tid];
        const float nd = n * d;
        const float rc = 1.0f / (n + EPS_N);
        s_layer[tid][0] = make_float4(nd, nd, n, n);
        s_layer[tid][1] = make_float4(rc, rc, 0.0f, 0.0f);
    }
    if (tid == INNER) {
        s_edge[0] = n_layers[b * NL];                      // n_in
        s_edge[1] = n_layers[b * NL + NL - 1];             // n_sub
    }
    __syncthreads();

    const float2 wl  = *(const float2*)&wavelengths[w0];
    const v2f invl = { 1.0f / wl.x, 1.0f / wl.y };         // k0 in revolutions

    v2f av = {1.0f, 1.0f};
    v2f bv = {0.0f, 0.0f};
    v2f cv = {0.0f, 0.0f};
    v2f dv = {1.0f, 1.0f};

    #pragma unroll
    for (int i = 0; i < INNER; ++i) {
        const float4 A  = s_layer[i][0];                   // ds_read_b128 (uniform bcast)
        const float2 Rr = *(const float2*)&s_layer[i][1];  // ds_read_b64
        const v2f nd2 = {A.x, A.y};                        // adjacent VGPRs from b128
        const v2f nn2 = {A.z, A.w};
        const v2f rr2 = {Rr.x, Rr.y};

        const v2f ph = nd2 * invl;                         // 1 pk_mul
        v2f s2, c2;
        s2.x = __builtin_amdgcn_sinf(ph.x);                // 4 trans
        s2.y = __builtin_amdgcn_sinf(ph.y);
        c2.x = __builtin_amdgcn_cosf(ph.x);
        c2.y = __builtin_amdgcn_cosf(ph.y);

        const v2f ns2 = nn2 * s2;                          // 1 pk_mul
        const v2f sn2 = rr2 * s2;                          // 1 pk_mul

        const v2f an = __builtin_elementwise_fma(bv,  ns2, av * c2);  // 8 pk
        const v2f bn = __builtin_elementwise_fma(-av, sn2, bv * c2);  // (neg folds)
        const v2f cn = __builtin_elementwise_fma(-dv, ns2, cv * c2);
        const v2f dn = __builtin_elementwise_fma(cv,  sn2, dv * c2);
        av = an; bv = bn; cv = cn; dv = dn;
    }

    const float n_in  = s_edge[0];
    const float n_sub = s_edge[1];

    // E = a + eps_Y + i*(b*n_sub);  H = d*n_sub + i*c;  R = |nE-H|^2 / |nE+H|^2
    float2 Rout;
    {
        const float Er = av.x + EPS_Y;
        const float Ei = bv.x * n_sub;
        const float Hr = dv.x * n_sub;
        const float Hi = cv.x;
        const float Nr = fmaf(n_in, Er, -Hr);
        const float Ni = fmaf(n_in, Ei, -Hi);
        const float Dr = fmaf(n_in, Er,  Hr);
        const float Di = fmaf(n_in, Ei,  Hi);
        Rout.x = (Nr * Nr + Ni * Ni) / (Dr * Dr + Di * Di);
    }
    {
        const float Er = av.y + EPS_Y;
        const float Ei = bv.y * n_sub;
        const float Hr = dv.y * n_sub;
        const float Hi = cv.y;
        const float Nr = fmaf(n_in, Er, -Hr);
        const float Ni = fmaf(n_in, Ei, -Hi);
        const float Dr = fmaf(n_in, Er,  Hr);
        const float Di = fmaf(n_in, Ei,  Hi);
        Rout.y = (Nr * Nr + Ni * Ni) / (Dr * Dr + Di * Di);
    }
    *(float2*)&out[b * W + w0] = Rout;     // coalesced 8B/lane store
}

extern "C" void kernel_launch(void* const* d_in, const int* in_sizes, int n_in,
                              void* d_out, int out_size, void* d_ws, size_t ws_size,
                              hipStream_t stream)
{
    const float* n_layers    = (const float*)d_in[0];
    const float* d_layers    = (const float*)d_in[1];
    const float* wavelengths = (const float*)d_in[2];
    float* out = (float*)d_out;

    dim3 grid(W / 512, B);                 // 2 wavelengths per thread
    dim3 block(256);
    tmm_kernel<<<grid, block, 0, stream>>>(n_layers, d_layers, wavelengths, out);
}